// Round 9
// baseline (2666.126 us; speedup 1.0000x reference)
//
#include <hip/hip_runtime.h>
#include <hip/hip_bf16.h>
#include <math.h>

#define S_LEN 64
#define T_LEN 32
#define BATCH 512
#define IN_DIM 66
#define INP 128         // IN_DIM zero-padded to multiple of 64
#define H_DIM 1024
#define O_DIM 1024
#define H3 3072

typedef __attribute__((ext_vector_type(8))) short short8;
typedef __attribute__((ext_vector_type(4))) float f32x4;
typedef __attribute__((ext_vector_type(4))) unsigned short us4;

__device__ __forceinline__ unsigned short f2b(float f) {
    union { float f; unsigned u; } x; x.f = f;
    unsigned r = x.u + 0x7FFF + ((x.u >> 16) & 1);
    return (unsigned short)(r >> 16);
}
__device__ __forceinline__ float b2f(unsigned short s) {
    union { unsigned u; float f; } x; x.u = ((unsigned)s) << 16;
    return x.f;
}
// async global->LDS, 16B per lane; lds base must be wave-uniform
__device__ __forceinline__ void gll16(const void* g, const void* l) {
    __builtin_amdgcn_global_load_lds(
        (const __attribute__((address_space(1))) unsigned int*)g,
        (__attribute__((address_space(3))) unsigned int*)l, 16, 0, 0);
}
template<int N>
__device__ __forceinline__ void vmwait() {
    if constexpr (N == 0) asm volatile("s_waitcnt vmcnt(0)" ::: "memory");
    else if constexpr (N == 2) asm volatile("s_waitcnt vmcnt(2)" ::: "memory");
    else if constexpr (N == 4) asm volatile("s_waitcnt vmcnt(4)" ::: "memory");
    else if constexpr (N == 8) asm volatile("s_waitcnt vmcnt(8)" ::: "memory");
}
__device__ __forceinline__ void sbar() { __builtin_amdgcn_s_barrier(); }
__device__ __forceinline__ void schedbar() { __builtin_amdgcn_sched_barrier(0); }

// ---------------------------------------------------------------------------
// MFMA GEMM, bf16: C[M,N] = A@W^T, tile TM x TN. lda/ldw mult of 8, K mult 32.
// flags: 1 bias, 2 add fp32, 4 add bf16, 8 relu, 16 store f32, 32 store bf16
// ---------------------------------------------------------------------------
template<int TM, int TN>
__global__ __launch_bounds__(256) void gemm_k(
    const unsigned short* __restrict__ A, int lda,
    const unsigned short* __restrict__ W, int ldw,
    const float* __restrict__ bias,
    const float* __restrict__ addf, const unsigned short* __restrict__ addb,
    int ldadd,
    float* __restrict__ Cf,
    unsigned short* __restrict__ Cb, int ldc,
    int K, int flags)
{
    constexpr int IF = TM / 16;   // A frags per wave
    constexpr int JF = TN / 64;   // B frags per wave
    constexpr int NW = TN / 4;    // cols per wave
    constexpr int CA = TM * 4;    // 16B chunks in A tile
    constexpr int CW = TN * 4;
    constexpr bool PIPE = (CA >= 256) && (CW >= 256);  // uniform loads/thread
    constexpr int PT = (CA + CW) / 256;                // loads per thread per tile
    __shared__ __align__(16) unsigned short As[2][TM * 32];
    __shared__ __align__(16) unsigned short Bs[2][TN * 32];

    const int bm = blockIdx.y * TM;
    const int bn = blockIdx.x * TN;
    const int t = threadIdx.x;
    const int lane = t & 63;
    const int wv = t >> 6;
    const int ln = lane & 15;
    const int quad = lane >> 4;

    f32x4 acc[IF][JF];
    #pragma unroll
    for (int i = 0; i < IF; i++)
        #pragma unroll
        for (int j = 0; j < JF; j++) {
            f32x4 z = {0.f, 0.f, 0.f, 0.f};
            acc[i][j] = z;
        }

    auto stage = [&](int buf, int k0) {
        if constexpr (CA >= 256) {
            #pragma unroll
            for (int j = 0; j < CA / 256; j++) {
                int ch = j * 256 + t;
                gll16(A + (size_t)(bm + (ch >> 2)) * lda + k0 + (ch & 3) * 8,
                      (const char*)As[buf] + (j * 4 + wv) * 1024);
            }
        } else {
            if (t < CA)
                gll16(A + (size_t)(bm + (t >> 2)) * lda + k0 + (t & 3) * 8,
                      (const char*)As[buf] + wv * 1024);
        }
        if constexpr (CW >= 256) {
            #pragma unroll
            for (int j = 0; j < CW / 256; j++) {
                int ch = j * 256 + t;
                gll16(W + (size_t)(bn + (ch >> 2)) * ldw + k0 + (ch & 3) * 8,
                      (const char*)Bs[buf] + (j * 4 + wv) * 1024);
            }
        } else {
            if (t < CW)
                gll16(W + (size_t)(bn + (t >> 2)) * ldw + k0 + (t & 3) * 8,
                      (const char*)Bs[buf] + wv * 1024);
        }
    };

    auto comp = [&](int cur) {
        short8 af[IF], bf[JF];
        #pragma unroll
        for (int ii = 0; ii < IF; ii++)
            af[ii] = *(const short8*)&As[cur][(ii * 16 + ln) * 32 + quad * 8];
        #pragma unroll
        for (int j = 0; j < JF; j++)
            bf[j] = *(const short8*)&Bs[cur][(wv * NW + j * 16 + ln) * 32 + quad * 8];
        #pragma unroll
        for (int ii = 0; ii < IF; ii++)
            #pragma unroll
            for (int j = 0; j < JF; j++)
                acc[ii][j] = __builtin_amdgcn_mfma_f32_16x16x32_bf16(
                    af[ii], bf[j], acc[ii][j], 0, 0, 0);
    };

    const int nt = K >> 5;
    if constexpr (PIPE) {
        stage(0, 0);
        for (int i = 0; i < nt; ++i) {
            const int cur = i & 1;
            if (i + 1 < nt) { stage(cur ^ 1, (i + 1) << 5); vmwait<PT>(); }
            else            { vmwait<0>(); }
            schedbar();
            sbar();
            schedbar();
            comp(cur);
            schedbar();
            sbar();
        }
    } else {
        stage(0, 0);
        __syncthreads();
        for (int i = 0; i < nt; ++i) {
            const int cur = i & 1;
            if (i + 1 < nt) stage(cur ^ 1, (i + 1) << 5);
            comp(cur);
            __syncthreads();
        }
    }

    #pragma unroll
    for (int i = 0; i < IF; i++) {
        #pragma unroll
        for (int j = 0; j < JF; j++) {
            #pragma unroll
            for (int r = 0; r < 4; r++) {
                int m = bm + i * 16 + quad * 4 + r;
                int n = bn + wv * NW + j * 16 + ln;
                float v = acc[i][j][r];
                if (flags & 1) v += bias[n];
                if (flags & 2) v += addf[(size_t)m * ldadd + n];
                if (flags & 4) v += b2f(addb[(size_t)m * ldadd + n]);
                if (flags & 8) v = fmaxf(v, 0.f);
                if (flags & 16) Cf[(size_t)m * ldc + n] = v;
                if (flags & 32) Cb[(size_t)m * ldc + n] = f2b(v);
            }
        }
    }
}

// ---------------------------------------------------------------------------
// GRU tile stage/compute (32x32 tile, 256 threads, 2-group K-split).
// ---------------------------------------------------------------------------
__device__ __forceinline__ void gru_stage(
    const unsigned short* __restrict__ A, int lda,
    const unsigned short* __restrict__ W, int ldw, int kb,
    unsigned short* As_g, unsigned short* Ws_g,
    int bm, int bn, int gt)
{
    const int gwv = gt >> 6;
    #pragma unroll
    for (int j = 0; j < 2; j++) {
        int ch = j * 128 + gt;
        int s = ch >> 7, r = (ch >> 2) & 31, c = ch & 3;
        gll16(A + (size_t)(bm + r) * lda + kb + s * 32 + c * 8,
              (const char*)As_g + j * 2048 + gwv * 1024);
    }
    #pragma unroll
    for (int j = 0; j < 6; j++) {
        int ch = j * 128 + gt;
        int g = ch >> 8, ch2 = ch & 255;
        int s = ch2 >> 7, w = (ch2 >> 2) & 31, c = ch2 & 3;
        gll16(W + (size_t)(g * H_DIM + bn + w) * ldw + kb + s * 32 + c * 8,
              (const char*)Ws_g + j * 2048 + gwv * 1024);
    }
}

__device__ __forceinline__ void gru_compute(
    const unsigned short* As_g, const unsigned short* Ws_g,
    int gwv, int ln, int quad,
    f32x4 (&accR)[2], f32x4 (&accZ)[2], f32x4 (&accN)[2])
{
    #pragma unroll
    for (int sub = 0; sub < 2; sub++) {
        short8 a[2], bw[3];
        #pragma unroll
        for (int i = 0; i < 2; i++)
            a[i] = *(const short8*)&As_g[sub * 1024 + (i * 16 + ln) * 32 + quad * 8];
        #pragma unroll
        for (int g = 0; g < 3; g++)
            bw[g] = *(const short8*)&Ws_g[g * 2048 + sub * 1024 + (gwv * 16 + ln) * 32 + quad * 8];
        #pragma unroll
        for (int i = 0; i < 2; i++) {
            accR[i] = __builtin_amdgcn_mfma_f32_16x16x32_bf16(a[i], bw[0], accR[i], 0, 0, 0);
            accZ[i] = __builtin_amdgcn_mfma_f32_16x16x32_bf16(a[i], bw[1], accZ[i], 0, 0, 0);
            accN[i] = __builtin_amdgcn_mfma_f32_16x16x32_bf16(a[i], bw[2], accN[i], 0, 0, 0);
        }
    }
}

// ---------------------------------------------------------------------------
// Fused GRU step, 256 threads, tile 32x32, 64 KB LDS -> 2 blocks/CU.
// Counted-vmcnt pipeline. Grid (32,16) = 512 blocks.
// gi != null: input gates precomputed (gix[m, g*H+n], bias-free) -> skip
// phase 0 entirely (caller passes K0 = 0); epilogue adds gi terms.
// ---------------------------------------------------------------------------
__global__ __launch_bounds__(256) void gru_gemm(
    const unsigned short* __restrict__ A0, int lda0,
    const unsigned short* __restrict__ W0, int ldw0, int K0,
    const unsigned short* __restrict__ A1,   // hb_in [512,1024]
    const unsigned short* __restrict__ W1,   // Whh   [3072,1024]
    const float* __restrict__ bih, const float* __restrict__ bhh,
    const float* __restrict__ hf_in, float* __restrict__ hf_out,
    unsigned short* __restrict__ hb_out, unsigned short* __restrict__ slot,
    const unsigned short* __restrict__ gi)   // [512, 3072] or null
{
    __shared__ __align__(16) unsigned short As2[2][2][2048];   // 16 KB
    __shared__ __align__(16) unsigned short Ws2[2][2][6144];   // 48 KB
    const int bn = blockIdx.x * 32;
    const int bm = blockIdx.y * 32;
    const int t = threadIdx.x;            // 0..255
    const int wg = t >> 7;                // K-split group
    const int gt = t & 127;               // thread in group
    const int lane = t & 63;
    const int gwv = gt >> 6;              // wave within group (0,1)
    const int ln = lane & 15;
    const int quad = lane >> 4;

    f32x4 accR[2], accZ[2], accN0[2], accN1[2];
    #pragma unroll
    for (int i = 0; i < 2; i++) {
        f32x4 z = {0.f, 0.f, 0.f, 0.f};
        accR[i] = z; accZ[i] = z; accN0[i] = z; accN1[i] = z;
    }

    const int half0 = K0 >> 1;            // multiple of 64 (0 when gi path)
    const int nt0 = half0 >> 6;           // phase-0 tiles per group
    const int nt = nt0 + 8;               // + phase-1 tiles (512/64)

    auto stg = [&](int i, int buf) {
        const unsigned short* A; int lda; const unsigned short* W; int ldw; int kb;
        if (i < nt0) { A = A0; lda = lda0; W = W0; ldw = ldw0; kb = wg * half0 + (i << 6); }
        else         { A = A1; lda = H_DIM; W = W1; ldw = H_DIM; kb = wg * 512 + ((i - nt0) << 6); }
        gru_stage(A, lda, W, ldw, kb, As2[wg][buf], Ws2[wg][buf], bm, bn, gt);
    };

    stg(0, 0);
    for (int i = 0; i < nt; ++i) {
        const int cur = i & 1;
        if (i + 1 < nt) { stg(i + 1, cur ^ 1); vmwait<8>(); }
        else            { vmwait<0>(); }
        schedbar();
        sbar();
        schedbar();
        if (i < nt0)
            gru_compute(As2[wg][cur], Ws2[wg][cur], gwv, ln, quad, accR, accZ, accN0);
        else
            gru_compute(As2[wg][cur], Ws2[wg][cur], gwv, ln, quad, accR, accZ, accN1);
        schedbar();
        sbar();
    }

    // ---- cross-group reduction (stride 33 floats: conflict-free) ----
    float* red = (float*)Ws2;
    const int rb = (gwv * 64 + lane) * 33;
    if (wg == 1) {
        #pragma unroll
        for (int i = 0; i < 2; i++)
            #pragma unroll
            for (int r = 0; r < 4; r++) {
                red[rb + i * 4 + r]      = accR[i][r];
                red[rb + 8 + i * 4 + r]  = accZ[i][r];
                red[rb + 16 + i * 4 + r] = accN0[i][r];
                red[rb + 24 + i * 4 + r] = accN1[i][r];
            }
    }
    __syncthreads();
    if (wg == 0) {
        #pragma unroll
        for (int i = 0; i < 2; i++)
            #pragma unroll
            for (int r = 0; r < 4; r++) {
                accR[i][r]  += red[rb + i * 4 + r];
                accZ[i][r]  += red[rb + 8 + i * 4 + r];
                accN0[i][r] += red[rb + 16 + i * 4 + r];
                accN1[i][r] += red[rb + 24 + i * 4 + r];
            }
        const int n = bn + gwv * 16 + ln;
        const float br = bih[n] + bhh[n];
        const float bz = bih[H_DIM + n] + bhh[H_DIM + n];
        const float bi_n = bih[2 * H_DIM + n];
        const float bh_n = bhh[2 * H_DIM + n];
        #pragma unroll
        for (int i = 0; i < 2; i++) {
            #pragma unroll
            for (int r = 0; r < 4; r++) {
                const int m = bm + i * 16 + quad * 4 + r;
                const size_t idx = (size_t)m * H_DIM + n;
                float giR = 0.f, giZ = 0.f, giN = 0.f;
                if (gi) {
                    const size_t gb = (size_t)m * H3 + n;
                    giR = b2f(gi[gb]);
                    giZ = b2f(gi[gb + H_DIM]);
                    giN = b2f(gi[gb + 2 * H_DIM]);
                }
                float rg = 1.f / (1.f + __expf(-(accR[i][r] + giR + br)));
                float zg = 1.f / (1.f + __expf(-(accZ[i][r] + giZ + bz)));
                float av = accN0[i][r] + giN + bi_n + rg * (accN1[i][r] + bh_n);
                float e2 = __expf(-2.f * fabsf(av));
                float th = (1.f - e2) / (1.f + e2);
                th = av < 0.f ? -th : th;
                float o = (1.f - zg) * th + zg * hf_in[idx];
                hf_out[idx] = o;
                unsigned short ob = f2b(o);
                hb_out[idx] = ob;
                if (slot) slot[idx] = ob;
            }
        }
    }
}

// ---------------------------------------------------------------------------
// Fused attention + comb (decoder step):
// scores = h@wAhT + attnx -> softmax -> comb = relu(sum_l aw[l]*encWc[l,b,:]
// + combx[td,b,:]). encWc[l] = encb[l]@Wcc^T precomputed (linearity).
// ---------------------------------------------------------------------------
__global__ __launch_bounds__(256) void attn_comb(
    const unsigned short* __restrict__ hb,     // [512,1024] bf16
    const unsigned short* __restrict__ wAhT,   // [1024][64] bf16 (k-major)
    const unsigned short* __restrict__ attnx_t,// [512,64] bf16 (incl bias)
    const unsigned short* __restrict__ encWc,  // [64,512,1024] bf16
    const unsigned short* __restrict__ combx_t,// [512,1024] bf16 (incl bias)
    unsigned short* __restrict__ comb)         // [512,1024] bf16
{
    __shared__ float hf[H_DIM];
    __shared__ float part[4][S_LEN];
    __shared__ float awl[S_LEN];
    const int b = blockIdx.x, t = threadIdx.x;
    {
        us4 u = *(const us4*)(hb + ((size_t)b << 10) + t * 4);
        #pragma unroll
        for (int j = 0; j < 4; j++) hf[t * 4 + j] = b2f(u[j]);
    }
    __syncthreads();
    {
        const int c = t & 63, ks = (t >> 6) * 256;
        float s = 0.f;
        #pragma unroll 8
        for (int k = 0; k < 256; k++)
            s += hf[ks + k] * b2f(wAhT[(size_t)(ks + k) * S_LEN + c]);
        part[t >> 6][c] = s;
    }
    __syncthreads();
    if (t < 64) {
        float v = part[0][t] + part[1][t] + part[2][t] + part[3][t]
                + b2f(attnx_t[b * S_LEN + t]);
        float m = v;
        #pragma unroll
        for (int off = 32; off; off >>= 1) m = fmaxf(m, __shfl_xor(m, off));
        float e = __expf(v - m);
        float ss = e;
        #pragma unroll
        for (int off = 32; off; off >>= 1) ss += __shfl_xor(ss, off);
        awl[t] = e / ss;
    }
    __syncthreads();
    const int hq = t * 4;
    float s0 = 0.f, s1 = 0.f, s2 = 0.f, s3 = 0.f;
    #pragma unroll 4
    for (int l = 0; l < S_LEN; l++) {
        us4 u = *(const us4*)(encWc + (((size_t)l * BATCH + b) << 10) + hq);
        float w = awl[l];
        s0 += w * b2f(u[0]); s1 += w * b2f(u[1]);
        s2 += w * b2f(u[2]); s3 += w * b2f(u[3]);
    }
    us4 cx = *(const us4*)(combx_t + ((size_t)b << 10) + hq);
    s0 = fmaxf(s0 + b2f(cx[0]), 0.f);
    s1 = fmaxf(s1 + b2f(cx[1]), 0.f);
    s2 = fmaxf(s2 + b2f(cx[2]), 0.f);
    s3 = fmaxf(s3 + b2f(cx[3]), 0.f);
    us4 o; o[0] = f2b(s0); o[1] = f2b(s1); o[2] = f2b(s2); o[3] = f2b(s3);
    *(us4*)(comb + ((size_t)b << 10) + hq) = o;
}

// Fallback: plain attention -> ctx (3-kernel decoder path, if ws too small)
__global__ __launch_bounds__(256) void attn_ctx(
    const unsigned short* __restrict__ hb,
    const unsigned short* __restrict__ wAhT,
    const unsigned short* __restrict__ attnx_t,
    const unsigned short* __restrict__ encb,
    unsigned short* __restrict__ ctx)
{
    __shared__ float hf[H_DIM];
    __shared__ float part[4][S_LEN];
    __shared__ float awl[S_LEN];
    const int b = blockIdx.x, t = threadIdx.x;
    {
        us4 u = *(const us4*)(hb + ((size_t)b << 10) + t * 4);
        #pragma unroll
        for (int j = 0; j < 4; j++) hf[t * 4 + j] = b2f(u[j]);
    }
    __syncthreads();
    {
        const int c = t & 63, ks = (t >> 6) * 256;
        float s = 0.f;
        #pragma unroll 8
        for (int k = 0; k < 256; k++)
            s += hf[ks + k] * b2f(wAhT[(size_t)(ks + k) * S_LEN + c]);
        part[t >> 6][c] = s;
    }
    __syncthreads();
    if (t < 64) {
        float v = part[0][t] + part[1][t] + part[2][t] + part[3][t]
                + b2f(attnx_t[b * S_LEN + t]);
        float m = v;
        #pragma unroll
        for (int off = 32; off; off >>= 1) m = fmaxf(m, __shfl_xor(m, off));
        float e = __expf(v - m);
        float ss = e;
        #pragma unroll
        for (int off = 32; off; off >>= 1) ss += __shfl_xor(ss, off);
        awl[t] = e / ss;
    }
    __syncthreads();
    const int hq = t * 4;
    float s0 = 0.f, s1 = 0.f, s2 = 0.f, s3 = 0.f;
    #pragma unroll 4
    for (int l = 0; l < S_LEN; l++) {
        us4 u = *(const us4*)(encb + (((size_t)l * BATCH + b) << 10) + hq);
        float w = awl[l];
        s0 += w * b2f(u[0]); s1 += w * b2f(u[1]);
        s2 += w * b2f(u[2]); s3 += w * b2f(u[3]);
    }
    us4 o; o[0] = f2b(s0); o[1] = f2b(s1); o[2] = f2b(s2); o[3] = f2b(s3);
    *(us4*)(ctx + ((size_t)b << 10) + hq) = o;
}

// ---------------------------------------------------------------------------
// One fused convert kernel: all fp32->bf16 preprocessing, grid-strided.
// ---------------------------------------------------------------------------
__global__ __launch_bounds__(256) void cvt_all(
    const float* __restrict__ enc_Whh, const float* __restrict__ dec_Wih,
    const float* __restrict__ dec_Whh, const float* __restrict__ comb_W,
    const float* __restrict__ out_W,   const float* __restrict__ attn_W,
    const float* __restrict__ enc_Wih, const float* __restrict__ input,
    const float* __restrict__ target,
    unsigned short* __restrict__ wWhh, unsigned short* __restrict__ wDih,
    unsigned short* __restrict__ wDhh, unsigned short* __restrict__ wCc,
    unsigned short* __restrict__ wCx,  unsigned short* __restrict__ wO,
    unsigned short* __restrict__ wAx,  unsigned short* __restrict__ wAhT,
    unsigned short* __restrict__ wIhp, unsigned short* __restrict__ xbp,
    unsigned short* __restrict__ targetb)
{
    const unsigned nW = H3 * H_DIM / 4;
    const unsigned nH = H_DIM * H_DIM / 4;
    const unsigned nA = S_LEN * H_DIM / 4;
    const unsigned nI = H3 * INP / 4;
    const unsigned nX = S_LEN * BATCH * INP / 4;
    const unsigned nT = T_LEN * BATCH * H_DIM / 4;
    const unsigned total = 3 * nW + 3 * nH + 2 * nA + nI + nX + nT;

    auto plain4 = [](const float* s, unsigned short* d, unsigned i) {
        f32x4 v = *(const f32x4*)(s + (size_t)i * 4);
        us4 o;
        #pragma unroll
        for (int j = 0; j < 4; j++) o[j] = f2b(v[j]);
        *(us4*)(d + (size_t)i * 4) = o;
    };
    auto strided4 = [](const float* s, int ld, int off, int c4s,
                       unsigned short* d, unsigned i) {
        int r = i / c4s, c4 = i - r * c4s;
        f32x4 v = *(const f32x4*)(s + (size_t)r * ld + off + c4 * 4);
        us4 o;
        #pragma unroll
        for (int j = 0; j < 4; j++) o[j] = f2b(v[j]);
        *(us4*)(d + (size_t)i * 4) = o;
    };
    auto pad4 = [](const float* s, unsigned short* d, unsigned i) {
        int r = i >> 5, c = (i & 31) * 4;
        us4 o;
        #pragma unroll
        for (int j = 0; j < 4; j++) {
            int cc = c + j;
            o[j] = (cc < IN_DIM) ? f2b(s[(size_t)r * IN_DIM + cc]) : (unsigned short)0;
        }
        *(us4*)(d + (size_t)r * INP + c) = o;
    };

    for (unsigned q = blockIdx.x * blockDim.x + threadIdx.x; q < total;
         q += gridDim.x * blockDim.x) {
        unsigned i = q;
        if (i < nW) { plain4(enc_Whh, wWhh, i); continue; }  i -= nW;
        if (i < nW) { plain4(dec_Wih, wDih, i); continue; }  i -= nW;
        if (i < nW) { plain4(dec_Whh, wDhh, i); continue; }  i -= nW;
        if (i < nH) { strided4(comb_W, 2 * H_DIM, H_DIM, H_DIM / 4, wCc, i); continue; }  i -= nH;
        if (i < nH) { strided4(comb_W, 2 * H_DIM, 0, H_DIM / 4, wCx, i); continue; }  i -= nH;
        if (i < nH) { plain4(out_W, wO, i); continue; }  i -= nH;
        if (i < nA) { strided4(attn_W, 2 * H_DIM, 0, H_DIM / 4, wAx, i); continue; }  i -= nA;
        if (i < nA) {
            int idx = i * 4, k = idx >> 6, c = idx & 63;
            us4 o;
            #pragma unroll
            for (int j = 0; j < 4; j++)
                o[j] = f2b(attn_W[(size_t)(c + j) * 2 * H_DIM + H_DIM + k]);
            *(us4*)(wAhT + idx) = o;
            continue;
        }  i -= nA;
        if (i < nI) { pad4(enc_Wih, wIhp, i); continue; }  i -= nI;
        if (i < nX) { pad4(input, xbp, i); continue; }  i -= nX;
        plain4(target, targetb, i);
    }
}

__global__ void log_softmax1024(float* __restrict__ x)
{
    __shared__ float red[256];
    float* xr = x + (size_t)blockIdx.x * O_DIM;
    int t = threadIdx.x;
    float m = -1e30f;
    for (int i = t; i < O_DIM; i += 256) m = fmaxf(m, xr[i]);
    red[t] = m; __syncthreads();
    for (int s2 = 128; s2 > 0; s2 >>= 1) {
        if (t < s2) red[t] = fmaxf(red[t], red[t + s2]);
        __syncthreads();
    }
    m = red[0];
    __syncthreads();
    float s = 0.f;
    for (int i = t; i < O_DIM; i += 256) s += expf(xr[i] - m);
    red[t] = s; __syncthreads();
    for (int s2 = 128; s2 > 0; s2 >>= 1) {
        if (t < s2) red[t] += red[t + s2];
        __syncthreads();
    }
    float lse = m + logf(red[0]);
    __syncthreads();
    for (int i = t; i < O_DIM; i += 256) xr[i] = xr[i] - lse;
}

// ---------------------------------------------------------------------------
extern "C" void kernel_launch(void* const* d_in, const int* in_sizes, int n_in,
                              void* d_out, int out_size, void* d_ws, size_t ws_size,
                              hipStream_t stream)
{
    const float* input   = (const float*)d_in[0];   // [S,B,IN]
    const float* target  = (const float*)d_in[1];   // [T,B,H]
    const float* enc_Wih = (const float*)d_in[2];
    const float* enc_Whh = (const float*)d_in[3];
    const float* enc_bih = (const float*)d_in[4];
    const float* enc_bhh = (const float*)d_in[5];
    const float* attn_W  = (const float*)d_in[6];   // [S,2H]
    const float* attn_b  = (const float*)d_in[7];
    const float* comb_W  = (const float*)d_in[8];   // [H,2H]
    const float* comb_b  = (const float*)d_in[9];
    const float* dec_Wih = (const float*)d_in[10];
    const float* dec_Whh = (const float*)d_in[11];
    const float* dec_bih = (const float*)d_in[12];
    const float* dec_bhh = (const float*)d_in[13];
    const float* out_W   = (const float*)d_in[14];
    const float* out_b   = (const float*)d_in[15];
    float* out = (float*)d_out;                     // [B,O] fp32

    // ---- workspace layout ----
    char* p = (char*)d_ws;
    auto alloc = [&](size_t bytes) {
        char* r = p; p += (bytes + 255) & ~(size_t)255; return r;
    };
    unsigned short* wWhh  = (unsigned short*)alloc((size_t)H3 * H_DIM * 2);
    unsigned short* wDih  = (unsigned short*)alloc((size_t)H3 * H_DIM * 2);
    unsigned short* wDhh  = (unsigned short*)alloc((size_t)H3 * H_DIM * 2);
    unsigned short* wCc   = (unsigned short*)alloc((size_t)H_DIM * H_DIM * 2);
    unsigned short* wCx   = (unsigned short*)alloc((size_t)H_DIM * H_DIM * 2);
    unsigned short* wO    = (unsigned short*)alloc((size_t)O_DIM * H_DIM * 2);
    unsigned short* wAhT  = (unsigned short*)alloc((size_t)H_DIM * S_LEN * 2);
    unsigned short* wAx   = (unsigned short*)alloc((size_t)S_LEN * H_DIM * 2);
    unsigned short* wIhp  = (unsigned short*)alloc((size_t)H3 * INP * 2);
    unsigned short* xbp   = (unsigned short*)alloc((size_t)S_LEN * BATCH * INP * 2);
    unsigned short* encb  = (unsigned short*)alloc((size_t)S_LEN * BATCH * H_DIM * 2);
    unsigned short* combx = (unsigned short*)alloc((size_t)(T_LEN - 1) * BATCH * H_DIM * 2);
    unsigned short* attnx = (unsigned short*)alloc((size_t)(T_LEN - 1) * BATCH * S_LEN * 2);
    float*          h     = (float*)alloc((size_t)BATCH * H_DIM * 4);
    unsigned short* hbA   = (unsigned short*)alloc((size_t)BATCH * H_DIM * 2);
    unsigned short* hbB   = (unsigned short*)alloc((size_t)BATCH * H_DIM * 2);
    unsigned short* ctx   = (unsigned short*)alloc((size_t)BATCH * H_DIM * 2);
    unsigned short* comb  = (unsigned short*)alloc((size_t)BATCH * H_DIM * 2);
    unsigned short* encWc = (unsigned short*)alloc((size_t)S_LEN * BATCH * H_DIM * 2);
    const bool fuse = ((size_t)(p - (char*)d_ws) <= ws_size);
    unsigned short* gix   = (unsigned short*)alloc((size_t)S_LEN * BATCH * H3 * 2);
    const bool fuseGi = ((size_t)(p - (char*)d_ws) <= ws_size);
    // targetb overlays encb: consumed (attnx/combx gemms) before encoder
    // writes encb.
    unsigned short* targetb = encb;

    const dim3 blk(256);

    hipMemsetAsync(h,   0, (size_t)BATCH * H_DIM * 4, stream);
    hipMemsetAsync(hbA, 0, (size_t)BATCH * H_DIM * 2, stream);

    // ---- one fused convert launch ----
    cvt_all<<<2048, blk, 0, stream>>>(
        enc_Whh, dec_Wih, dec_Whh, comb_W, out_W, attn_W, enc_Wih, input, target,
        wWhh, wDih, wDhh, wCc, wCx, wO, wAx, wAhT, wIhp, xbp, targetb);

    const int MT = (T_LEN - 1) * BATCH;  // 15872
    // attnx = target @ attn_W[:, :H]^T + attn_b
    gemm_k<64, 64><<<dim3(1, MT / 64), blk, 0, stream>>>(
        targetb, H_DIM, wAx, H_DIM, attn_b,
        nullptr, nullptr, 0, nullptr, attnx, S_LEN, H_DIM, 1 | 32);
    // combx = target @ comb_W[:, :H]^T + comb_b
    gemm_k<128, 128><<<dim3(H_DIM / 128, MT / 128), blk, 0, stream>>>(
        targetb, H_DIM, wCx, H_DIM, comb_b,
        nullptr, nullptr, 0, nullptr, combx, H_DIM, H_DIM, 1 | 32);
    // gix = x_all @ enc_Wih^T (bias-free), one parallel GEMM over all 64 steps
    if (fuseGi) {
        gemm_k<128, 128><<<dim3(H3 / 128, S_LEN * BATCH / 128), blk, 0, stream>>>(
            xbp, INP, wIhp, INP, nullptr,
            nullptr, nullptr, 0, nullptr, gix, H3, INP, 32);
    }

    const dim3 grid_gru(H_DIM / 32, BATCH / 32);   // 32 x 16 = 512 blocks
    unsigned short* hcur = hbA;
    unsigned short* hnxt = hbB;

    // ---------------- encoder: one kernel per step ----------------
    for (int s = 0; s < S_LEN; s++) {
        if (fuseGi) {
            gru_gemm<<<grid_gru, blk, 0, stream>>>(
                nullptr, 0, nullptr, 0, 0,
                hcur, wWhh, enc_bih, enc_bhh, h, h, hnxt,
                encb + (size_t)s * BATCH * H_DIM,
                gix + (size_t)s * BATCH * H3);
        } else {
            gru_gemm<<<grid_gru, blk, 0, stream>>>(
                xbp + (size_t)s * BATCH * INP, INP, wIhp, INP, INP,
                hcur, wWhh, enc_bih, enc_bhh, h, h, hnxt,
                encb + (size_t)s * BATCH * H_DIM, nullptr);
        }
        unsigned short* tmp = hcur; hcur = hnxt; hnxt = tmp;
    }

    if (fuse) {
        // encWc[l] = encb[l] @ wCc^T  (one parallel GEMM, M = 64*512)
        gemm_k<128, 128><<<dim3(H_DIM / 128, S_LEN * BATCH / 128), blk, 0, stream>>>(
            encb, H_DIM, wCc, H_DIM, nullptr,
            nullptr, nullptr, 0, nullptr, encWc, H_DIM, H_DIM, 32);
        // ---------------- decoder: TWO kernels per step ----------------
        for (int t = 0; t < T_LEN - 1; t++) {
            attn_comb<<<BATCH, blk, 0, stream>>>(
                hcur, wAhT, attnx + (size_t)t * BATCH * S_LEN, encWc,
                combx + (size_t)t * BATCH * H_DIM, comb);
            gru_gemm<<<grid_gru, blk, 0, stream>>>(
                comb, H_DIM, wDih, H_DIM, H_DIM,
                hcur, wDhh, dec_bih, dec_bhh, h, h, hnxt, nullptr, nullptr);
            unsigned short* tmp = hcur; hcur = hnxt; hnxt = tmp;
        }
    } else {
        // fallback: 3 kernels per step (no encWc buffer)
        for (int t = 0; t < T_LEN - 1; t++) {
            attn_ctx<<<BATCH, blk, 0, stream>>>(
                hcur, wAhT, attnx + (size_t)t * BATCH * S_LEN, encb, ctx);
            gemm_k<32, 64><<<dim3(H_DIM / 64, BATCH / 32), blk, 0, stream>>>(
                ctx, H_DIM, wCc, H_DIM, nullptr,
                nullptr, combx + (size_t)t * BATCH * H_DIM, H_DIM,
                nullptr, comb, H_DIM, H_DIM, 4 | 8 | 32);
            gru_gemm<<<grid_gru, blk, 0, stream>>>(
                comb, H_DIM, wDih, H_DIM, H_DIM,
                hcur, wDhh, dec_bih, dec_bhh, h, h, hnxt, nullptr, nullptr);
            unsigned short* tmp = hcur; hcur = hnxt; hnxt = tmp;
        }
    }

    // ---------------- output ----------------
    gemm_k<32, 64><<<dim3(O_DIM / 64, BATCH / 32), blk, 0, stream>>>(
        hcur, H_DIM, wO, H_DIM, out_b,
        nullptr, nullptr, 0, out, nullptr, O_DIM, H_DIM, 1 | 16);
    log_softmax1024<<<BATCH, blk, 0, stream>>>(out);
}

// Round 10
// 2658.978 us; speedup vs baseline: 1.0027x; 1.0027x over previous
//
#include <hip/hip_runtime.h>
#include <hip/hip_bf16.h>
#include <math.h>

#define S_LEN 64
#define T_LEN 32
#define BATCH 512
#define IN_DIM 66
#define INP 128         // IN_DIM zero-padded to multiple of 64
#define H_DIM 1024
#define O_DIM 1024
#define H3 3072

typedef __attribute__((ext_vector_type(8))) short short8;
typedef __attribute__((ext_vector_type(4))) float f32x4;
typedef __attribute__((ext_vector_type(4))) unsigned short us4;

__device__ __forceinline__ unsigned short f2b(float f) {
    union { float f; unsigned u; } x; x.f = f;
    unsigned r = x.u + 0x7FFF + ((x.u >> 16) & 1);
    return (unsigned short)(r >> 16);
}
__device__ __forceinline__ float b2f(unsigned short s) {
    union { unsigned u; float f; } x; x.u = ((unsigned)s) << 16;
    return x.f;
}
// async global->LDS, 16B per lane; lds base must be wave-uniform
__device__ __forceinline__ void gll16(const void* g, const void* l) {
    __builtin_amdgcn_global_load_lds(
        (const __attribute__((address_space(1))) unsigned int*)g,
        (__attribute__((address_space(3))) unsigned int*)l, 16, 0, 0);
}
template<int N>
__device__ __forceinline__ void vmwait() {
    if constexpr (N == 0) asm volatile("s_waitcnt vmcnt(0)" ::: "memory");
    else if constexpr (N == 2) asm volatile("s_waitcnt vmcnt(2)" ::: "memory");
    else if constexpr (N == 4) asm volatile("s_waitcnt vmcnt(4)" ::: "memory");
    else if constexpr (N == 5) asm volatile("s_waitcnt vmcnt(5)" ::: "memory");
    else if constexpr (N == 8) asm volatile("s_waitcnt vmcnt(8)" ::: "memory");
}
__device__ __forceinline__ void sbar() { __builtin_amdgcn_s_barrier(); }
__device__ __forceinline__ void schedbar() { __builtin_amdgcn_sched_barrier(0); }

// ---------------------------------------------------------------------------
// MFMA GEMM, bf16: C[M,N] = A@W^T, tile TM x TN. lda/ldw mult of 8, K mult 32.
// flags: 1 bias, 2 add fp32, 4 add bf16, 8 relu, 16 store f32, 32 store bf16
// ---------------------------------------------------------------------------
template<int TM, int TN>
__global__ __launch_bounds__(256) void gemm_k(
    const unsigned short* __restrict__ A, int lda,
    const unsigned short* __restrict__ W, int ldw,
    const float* __restrict__ bias,
    const float* __restrict__ addf, const unsigned short* __restrict__ addb,
    int ldadd,
    float* __restrict__ Cf,
    unsigned short* __restrict__ Cb, int ldc,
    int K, int flags)
{
    constexpr int IF = TM / 16;   // A frags per wave
    constexpr int JF = TN / 64;   // B frags per wave
    constexpr int NW = TN / 4;    // cols per wave
    constexpr int CA = TM * 4;    // 16B chunks in A tile
    constexpr int CW = TN * 4;
    constexpr bool PIPE = (CA >= 256) && (CW >= 256);  // uniform loads/thread
    constexpr int PT = (CA + CW) / 256;                // loads per thread per tile
    __shared__ __align__(16) unsigned short As[2][TM * 32];
    __shared__ __align__(16) unsigned short Bs[2][TN * 32];

    const int bm = blockIdx.y * TM;
    const int bn = blockIdx.x * TN;
    const int t = threadIdx.x;
    const int lane = t & 63;
    const int wv = t >> 6;
    const int ln = lane & 15;
    const int quad = lane >> 4;

    f32x4 acc[IF][JF];
    #pragma unroll
    for (int i = 0; i < IF; i++)
        #pragma unroll
        for (int j = 0; j < JF; j++) {
            f32x4 z = {0.f, 0.f, 0.f, 0.f};
            acc[i][j] = z;
        }

    auto stage = [&](int buf, int k0) {
        if constexpr (CA >= 256) {
            #pragma unroll
            for (int j = 0; j < CA / 256; j++) {
                int ch = j * 256 + t;
                gll16(A + (size_t)(bm + (ch >> 2)) * lda + k0 + (ch & 3) * 8,
                      (const char*)As[buf] + (j * 4 + wv) * 1024);
            }
        } else {
            if (t < CA)
                gll16(A + (size_t)(bm + (t >> 2)) * lda + k0 + (t & 3) * 8,
                      (const char*)As[buf] + wv * 1024);
        }
        if constexpr (CW >= 256) {
            #pragma unroll
            for (int j = 0; j < CW / 256; j++) {
                int ch = j * 256 + t;
                gll16(W + (size_t)(bn + (ch >> 2)) * ldw + k0 + (ch & 3) * 8,
                      (const char*)Bs[buf] + (j * 4 + wv) * 1024);
            }
        } else {
            if (t < CW)
                gll16(W + (size_t)(bn + (t >> 2)) * ldw + k0 + (t & 3) * 8,
                      (const char*)Bs[buf] + wv * 1024);
        }
    };

    auto comp = [&](int cur) {
        short8 af[IF], bf[JF];
        #pragma unroll
        for (int ii = 0; ii < IF; ii++)
            af[ii] = *(const short8*)&As[cur][(ii * 16 + ln) * 32 + quad * 8];
        #pragma unroll
        for (int j = 0; j < JF; j++)
            bf[j] = *(const short8*)&Bs[cur][(wv * NW + j * 16 + ln) * 32 + quad * 8];
        #pragma unroll
        for (int ii = 0; ii < IF; ii++)
            #pragma unroll
            for (int j = 0; j < JF; j++)
                acc[ii][j] = __builtin_amdgcn_mfma_f32_16x16x32_bf16(
                    af[ii], bf[j], acc[ii][j], 0, 0, 0);
    };

    const int nt = K >> 5;
    if constexpr (PIPE) {
        stage(0, 0);
        for (int i = 0; i < nt; ++i) {
            const int cur = i & 1;
            if (i + 1 < nt) { stage(cur ^ 1, (i + 1) << 5); vmwait<PT>(); }
            else            { vmwait<0>(); }
            schedbar();
            sbar();
            schedbar();
            comp(cur);
            schedbar();
            sbar();
        }
    } else {
        stage(0, 0);
        __syncthreads();
        for (int i = 0; i < nt; ++i) {
            const int cur = i & 1;
            if (i + 1 < nt) stage(cur ^ 1, (i + 1) << 5);
            comp(cur);
            __syncthreads();
        }
    }

    #pragma unroll
    for (int i = 0; i < IF; i++) {
        #pragma unroll
        for (int j = 0; j < JF; j++) {
            #pragma unroll
            for (int r = 0; r < 4; r++) {
                int m = bm + i * 16 + quad * 4 + r;
                int n = bn + wv * NW + j * 16 + ln;
                float v = acc[i][j][r];
                if (flags & 1) v += bias[n];
                if (flags & 2) v += addf[(size_t)m * ldadd + n];
                if (flags & 4) v += b2f(addb[(size_t)m * ldadd + n]);
                if (flags & 8) v = fmaxf(v, 0.f);
                if (flags & 16) Cf[(size_t)m * ldc + n] = v;
                if (flags & 32) Cb[(size_t)m * ldc + n] = f2b(v);
            }
        }
    }
}

// ---------------------------------------------------------------------------
// GRU tile stage/compute: tile 32 batch x 16 cols, 256 threads = 2 K-groups
// x 2 waves. Per group per buffer: As 4 KB ([sub2][row32][k32]), Ws 6 KB
// ([gate3][sub2][col16][k32]). 5 gll16/thread/tile (2 A + 3 W), uniform.
// ---------------------------------------------------------------------------
__device__ __forceinline__ void gru_stage(
    const unsigned short* __restrict__ A, int lda,
    const unsigned short* __restrict__ W, int ldw, int kb,
    unsigned short* As_g, unsigned short* Ws_g,
    int bm, int bn, int gt)
{
    const int gwv = gt >> 6;
    // A: 256 chunks (2/thread): ch -> sub ch>>7, row (ch>>2)&31, kchunk ch&3
    #pragma unroll
    for (int j = 0; j < 2; j++) {
        int ch = j * 128 + gt;
        int s = ch >> 7, r = (ch >> 2) & 31, c = ch & 3;
        gll16(A + (size_t)(bm + r) * lda + kb + s * 32 + c * 8,
              (const char*)As_g + j * 2048 + gwv * 1024);
    }
    // W: 384 chunks (3/thread): ch -> gate ch>>7; ch2=ch&127: sub ch2>>6,
    // col (ch2>>2)&15, kchunk ch2&3
    #pragma unroll
    for (int j = 0; j < 3; j++) {
        int ch = j * 128 + gt;
        int g = ch >> 7, ch2 = ch & 127;
        int s = ch2 >> 6, w = (ch2 >> 2) & 15, c = ch2 & 3;
        gll16(W + (size_t)(g * H_DIM + bn + w) * ldw + kb + s * 32 + c * 8,
              (const char*)Ws_g + j * 2048 + gwv * 1024);
    }
}

// wave gwv computes rows gwv*16..gwv*16+15 of the 32-row tile, all 16 cols
__device__ __forceinline__ void gru_compute(
    const unsigned short* As_g, const unsigned short* Ws_g,
    int gwv, int ln, int quad,
    f32x4 &accR, f32x4 &accZ, f32x4 &accN)
{
    #pragma unroll
    for (int sub = 0; sub < 2; sub++) {
        short8 a = *(const short8*)&As_g[sub * 1024 + (gwv * 16 + ln) * 32 + quad * 8];
        short8 bw0 = *(const short8*)&Ws_g[0 * 1024 + sub * 512 + ln * 32 + quad * 8];
        short8 bw1 = *(const short8*)&Ws_g[1 * 1024 + sub * 512 + ln * 32 + quad * 8];
        short8 bw2 = *(const short8*)&Ws_g[2 * 1024 + sub * 512 + ln * 32 + quad * 8];
        accR = __builtin_amdgcn_mfma_f32_16x16x32_bf16(a, bw0, accR, 0, 0, 0);
        accZ = __builtin_amdgcn_mfma_f32_16x16x32_bf16(a, bw1, accZ, 0, 0, 0);
        accN = __builtin_amdgcn_mfma_f32_16x16x32_bf16(a, bw2, accN, 0, 0, 0);
    }
}

// ---------------------------------------------------------------------------
// Fused GRU step, 256 threads, tile 32 batch x 16 cols, 40 KB LDS ->
// FOUR blocks/CU (16 waves/CU = 4/SIMD: independent latency-bound K-chains
// interleave on the CU). Counted-vmcnt pipeline. Grid (64,16) = 1024 blocks;
// same-bn blocks are bid stride 64 (≡0 mod 8) -> one XCD -> W L2-resident.
// K0 multiple of 128; phase-1 K fixed at 1024.
// ---------------------------------------------------------------------------
__global__ __launch_bounds__(256) void gru_gemm(
    const unsigned short* __restrict__ A0, int lda0,
    const unsigned short* __restrict__ W0, int ldw0, int K0,
    const unsigned short* __restrict__ A1,   // hb_in [512,1024]
    const unsigned short* __restrict__ W1,   // Whh   [3072,1024]
    const float* __restrict__ bih, const float* __restrict__ bhh,
    const float* __restrict__ hf_in, float* __restrict__ hf_out,
    unsigned short* __restrict__ hb_out, unsigned short* __restrict__ slot)
{
    __shared__ __align__(16) unsigned short As2[2][2][2048];   // 16 KB
    __shared__ __align__(16) unsigned short Ws2[2][2][3072];   // 24 KB
    const int bn = blockIdx.x * 16;
    const int bm = blockIdx.y * 32;
    const int t = threadIdx.x;            // 0..255
    const int wg = t >> 7;                // K-split group
    const int gt = t & 127;               // thread in group
    const int lane = t & 63;
    const int gwv = gt >> 6;              // wave within group (0,1) = row half
    const int ln = lane & 15;
    const int quad = lane >> 4;

    f32x4 accR, accZ, accN0, accN1;
    {
        f32x4 z = {0.f, 0.f, 0.f, 0.f};
        accR = z; accZ = z; accN0 = z; accN1 = z;
    }

    const int half0 = K0 >> 1;            // multiple of 64
    const int nt0 = half0 >> 6;           // phase-0 tiles per group
    const int nt = nt0 + 8;               // + phase-1 tiles (512/64)

    auto stg = [&](int i, int buf) {
        const unsigned short* A; int lda; const unsigned short* W; int ldw; int kb;
        if (i < nt0) { A = A0; lda = lda0; W = W0; ldw = ldw0; kb = wg * half0 + (i << 6); }
        else         { A = A1; lda = H_DIM; W = W1; ldw = H_DIM; kb = wg * 512 + ((i - nt0) << 6); }
        gru_stage(A, lda, W, ldw, kb, As2[wg][buf], Ws2[wg][buf], bm, bn, gt);
    };

    stg(0, 0);
    for (int i = 0; i < nt; ++i) {
        const int cur = i & 1;
        if (i + 1 < nt) { stg(i + 1, cur ^ 1); vmwait<5>(); }
        else            { vmwait<0>(); }
        schedbar();
        sbar();                 // all waves: tile i complete in LDS
        schedbar();
        if (i < nt0)
            gru_compute(As2[wg][cur], Ws2[wg][cur], gwv, ln, quad, accR, accZ, accN0);
        else
            gru_compute(As2[wg][cur], Ws2[wg][cur], gwv, ln, quad, accR, accZ, accN1);
        schedbar();
        sbar();                 // all waves done computing tile i (buf reusable)
    }

    // ---- cross-group reduction (stride 17 floats: conflict-free) ----
    float* red = (float*)Ws2;             // 24 KB scratch, needs 8.7 KB
    const int rb = (gwv * 64 + lane) * 17;
    if (wg == 1) {
        #pragma unroll
        for (int r = 0; r < 4; r++) {
            red[rb + r]      = accR[r];
            red[rb + 4 + r]  = accZ[r];
            red[rb + 8 + r]  = accN0[r];
            red[rb + 12 + r] = accN1[r];
        }
    }
    __syncthreads();
    if (wg == 0) {
        #pragma unroll
        for (int r = 0; r < 4; r++) {
            accR[r]  += red[rb + r];
            accZ[r]  += red[rb + 4 + r];
            accN0[r] += red[rb + 8 + r];
            accN1[r] += red[rb + 12 + r];
        }
        const int n = bn + ln;
        const float br = bih[n] + bhh[n];
        const float bz = bih[H_DIM + n] + bhh[H_DIM + n];
        const float bi_n = bih[2 * H_DIM + n];
        const float bh_n = bhh[2 * H_DIM + n];
        #pragma unroll
        for (int r = 0; r < 4; r++) {
            const int m = bm + gwv * 16 + quad * 4 + r;
            const size_t idx = (size_t)m * H_DIM + n;
            float rg = 1.f / (1.f + __expf(-(accR[r] + br)));
            float zg = 1.f / (1.f + __expf(-(accZ[r] + bz)));
            float av = accN0[r] + bi_n + rg * (accN1[r] + bh_n);
            float e2 = __expf(-2.f * fabsf(av));
            float th = (1.f - e2) / (1.f + e2);
            th = av < 0.f ? -th : th;
            float o = (1.f - zg) * th + zg * hf_in[idx];
            hf_out[idx] = o;
            unsigned short ob = f2b(o);
            hb_out[idx] = ob;
            if (slot) slot[idx] = ob;
        }
    }
}

// ---------------------------------------------------------------------------
// Fused attention + comb (decoder step):
// scores = h@wAhT + attnx -> softmax -> comb = relu(sum_l aw[l]*encWc[l,b,:]
// + combx[td,b,:]). encWc[l] = encb[l]@Wcc^T precomputed (linearity).
// ---------------------------------------------------------------------------
__global__ __launch_bounds__(256) void attn_comb(
    const unsigned short* __restrict__ hb,     // [512,1024] bf16
    const unsigned short* __restrict__ wAhT,   // [1024][64] bf16 (k-major)
    const unsigned short* __restrict__ attnx_t,// [512,64] bf16 (incl bias)
    const unsigned short* __restrict__ encWc,  // [64,512,1024] bf16
    const unsigned short* __restrict__ combx_t,// [512,1024] bf16 (incl bias)
    unsigned short* __restrict__ comb)         // [512,1024] bf16
{
    __shared__ float hf[H_DIM];
    __shared__ float part[4][S_LEN];
    __shared__ float awl[S_LEN];
    const int b = blockIdx.x, t = threadIdx.x;
    {
        us4 u = *(const us4*)(hb + ((size_t)b << 10) + t * 4);
        #pragma unroll
        for (int j = 0; j < 4; j++) hf[t * 4 + j] = b2f(u[j]);
    }
    __syncthreads();
    {
        const int c = t & 63, ks = (t >> 6) * 256;
        float s = 0.f;
        #pragma unroll 8
        for (int k = 0; k < 256; k++)
            s += hf[ks + k] * b2f(wAhT[(size_t)(ks + k) * S_LEN + c]);
        part[t >> 6][c] = s;
    }
    __syncthreads();
    if (t < 64) {
        float v = part[0][t] + part[1][t] + part[2][t] + part[3][t]
                + b2f(attnx_t[b * S_LEN + t]);
        float m = v;
        #pragma unroll
        for (int off = 32; off; off >>= 1) m = fmaxf(m, __shfl_xor(m, off));
        float e = __expf(v - m);
        float ss = e;
        #pragma unroll
        for (int off = 32; off; off >>= 1) ss += __shfl_xor(ss, off);
        awl[t] = e / ss;
    }
    __syncthreads();
    const int hq = t * 4;
    float s0 = 0.f, s1 = 0.f, s2 = 0.f, s3 = 0.f;
    #pragma unroll 4
    for (int l = 0; l < S_LEN; l++) {
        us4 u = *(const us4*)(encWc + (((size_t)l * BATCH + b) << 10) + hq);
        float w = awl[l];
        s0 += w * b2f(u[0]); s1 += w * b2f(u[1]);
        s2 += w * b2f(u[2]); s3 += w * b2f(u[3]);
    }
    us4 cx = *(const us4*)(combx_t + ((size_t)b << 10) + hq);
    s0 = fmaxf(s0 + b2f(cx[0]), 0.f);
    s1 = fmaxf(s1 + b2f(cx[1]), 0.f);
    s2 = fmaxf(s2 + b2f(cx[2]), 0.f);
    s3 = fmaxf(s3 + b2f(cx[3]), 0.f);
    us4 o; o[0] = f2b(s0); o[1] = f2b(s1); o[2] = f2b(s2); o[3] = f2b(s3);
    *(us4*)(comb + ((size_t)b << 10) + hq) = o;
}

// Fallback: plain attention -> ctx (3-kernel decoder path, if ws too small)
__global__ __launch_bounds__(256) void attn_ctx(
    const unsigned short* __restrict__ hb,
    const unsigned short* __restrict__ wAhT,
    const unsigned short* __restrict__ attnx_t,
    const unsigned short* __restrict__ encb,
    unsigned short* __restrict__ ctx)
{
    __shared__ float hf[H_DIM];
    __shared__ float part[4][S_LEN];
    __shared__ float awl[S_LEN];
    const int b = blockIdx.x, t = threadIdx.x;
    {
        us4 u = *(const us4*)(hb + ((size_t)b << 10) + t * 4);
        #pragma unroll
        for (int j = 0; j < 4; j++) hf[t * 4 + j] = b2f(u[j]);
    }
    __syncthreads();
    {
        const int c = t & 63, ks = (t >> 6) * 256;
        float s = 0.f;
        #pragma unroll 8
        for (int k = 0; k < 256; k++)
            s += hf[ks + k] * b2f(wAhT[(size_t)(ks + k) * S_LEN + c]);
        part[t >> 6][c] = s;
    }
    __syncthreads();
    if (t < 64) {
        float v = part[0][t] + part[1][t] + part[2][t] + part[3][t]
                + b2f(attnx_t[b * S_LEN + t]);
        float m = v;
        #pragma unroll
        for (int off = 32; off; off >>= 1) m = fmaxf(m, __shfl_xor(m, off));
        float e = __expf(v - m);
        float ss = e;
        #pragma unroll
        for (int off = 32; off; off >>= 1) ss += __shfl_xor(ss, off);
        awl[t] = e / ss;
    }
    __syncthreads();
    const int hq = t * 4;
    float s0 = 0.f, s1 = 0.f, s2 = 0.f, s3 = 0.f;
    #pragma unroll 4
    for (int l = 0; l < S_LEN; l++) {
        us4 u = *(const us4*)(encb + (((size_t)l * BATCH + b) << 10) + hq);
        float w = awl[l];
        s0 += w * b2f(u[0]); s1 += w * b2f(u[1]);
        s2 += w * b2f(u[2]); s3 += w * b2f(u[3]);
    }
    us4 o; o[0] = f2b(s0); o[1] = f2b(s1); o[2] = f2b(s2); o[3] = f2b(s3);
    *(us4*)(ctx + ((size_t)b << 10) + hq) = o;
}

// ---------------------------------------------------------------------------
// One fused convert kernel: all fp32->bf16 preprocessing, grid-strided.
// ---------------------------------------------------------------------------
__global__ __launch_bounds__(256) void cvt_all(
    const float* __restrict__ enc_Whh, const float* __restrict__ dec_Wih,
    const float* __restrict__ dec_Whh, const float* __restrict__ comb_W,
    const float* __restrict__ out_W,   const float* __restrict__ attn_W,
    const float* __restrict__ enc_Wih, const float* __restrict__ input,
    const float* __restrict__ target,
    unsigned short* __restrict__ wWhh, unsigned short* __restrict__ wDih,
    unsigned short* __restrict__ wDhh, unsigned short* __restrict__ wCc,
    unsigned short* __restrict__ wCx,  unsigned short* __restrict__ wO,
    unsigned short* __restrict__ wAx,  unsigned short* __restrict__ wAhT,
    unsigned short* __restrict__ wIhp, unsigned short* __restrict__ xbp,
    unsigned short* __restrict__ targetb)
{
    const unsigned nW = H3 * H_DIM / 4;
    const unsigned nH = H_DIM * H_DIM / 4;
    const unsigned nA = S_LEN * H_DIM / 4;
    const unsigned nI = H3 * INP / 4;
    const unsigned nX = S_LEN * BATCH * INP / 4;
    const unsigned nT = T_LEN * BATCH * H_DIM / 4;
    const unsigned total = 3 * nW + 3 * nH + 2 * nA + nI + nX + nT;

    auto plain4 = [](const float* s, unsigned short* d, unsigned i) {
        f32x4 v = *(const f32x4*)(s + (size_t)i * 4);
        us4 o;
        #pragma unroll
        for (int j = 0; j < 4; j++) o[j] = f2b(v[j]);
        *(us4*)(d + (size_t)i * 4) = o;
    };
    auto strided4 = [](const float* s, int ld, int off, int c4s,
                       unsigned short* d, unsigned i) {
        int r = i / c4s, c4 = i - r * c4s;
        f32x4 v = *(const f32x4*)(s + (size_t)r * ld + off + c4 * 4);
        us4 o;
        #pragma unroll
        for (int j = 0; j < 4; j++) o[j] = f2b(v[j]);
        *(us4*)(d + (size_t)i * 4) = o;
    };
    auto pad4 = [](const float* s, unsigned short* d, unsigned i) {
        int r = i >> 5, c = (i & 31) * 4;
        us4 o;
        #pragma unroll
        for (int j = 0; j < 4; j++) {
            int cc = c + j;
            o[j] = (cc < IN_DIM) ? f2b(s[(size_t)r * IN_DIM + cc]) : (unsigned short)0;
        }
        *(us4*)(d + (size_t)r * INP + c) = o;
    };

    for (unsigned q = blockIdx.x * blockDim.x + threadIdx.x; q < total;
         q += gridDim.x * blockDim.x) {
        unsigned i = q;
        if (i < nW) { plain4(enc_Whh, wWhh, i); continue; }  i -= nW;
        if (i < nW) { plain4(dec_Wih, wDih, i); continue; }  i -= nW;
        if (i < nW) { plain4(dec_Whh, wDhh, i); continue; }  i -= nW;
        if (i < nH) { strided4(comb_W, 2 * H_DIM, H_DIM, H_DIM / 4, wCc, i); continue; }  i -= nH;
        if (i < nH) { strided4(comb_W, 2 * H_DIM, 0, H_DIM / 4, wCx, i); continue; }  i -= nH;
        if (i < nH) { plain4(out_W, wO, i); continue; }  i -= nH;
        if (i < nA) { strided4(attn_W, 2 * H_DIM, 0, H_DIM / 4, wAx, i); continue; }  i -= nA;
        if (i < nA) {
            int idx = i * 4, k = idx >> 6, c = idx & 63;
            us4 o;
            #pragma unroll
            for (int j = 0; j < 4; j++)
                o[j] = f2b(attn_W[(size_t)(c + j) * 2 * H_DIM + H_DIM + k]);
            *(us4*)(wAhT + idx) = o;
            continue;
        }  i -= nA;
        if (i < nI) { pad4(enc_Wih, wIhp, i); continue; }  i -= nI;
        if (i < nX) { pad4(input, xbp, i); continue; }  i -= nX;
        plain4(target, targetb, i);
    }
}

__global__ void log_softmax1024(float* __restrict__ x)
{
    __shared__ float red[256];
    float* xr = x + (size_t)blockIdx.x * O_DIM;
    int t = threadIdx.x;
    float m = -1e30f;
    for (int i = t; i < O_DIM; i += 256) m = fmaxf(m, xr[i]);
    red[t] = m; __syncthreads();
    for (int s2 = 128; s2 > 0; s2 >>= 1) {
        if (t < s2) red[t] = fmaxf(red[t], red[t + s2]);
        __syncthreads();
    }
    m = red[0];
    __syncthreads();
    float s = 0.f;
    for (int i = t; i < O_DIM; i += 256) s += expf(xr[i] - m);
    red[t] = s; __syncthreads();
    for (int s2 = 128; s2 > 0; s2 >>= 1) {
        if (t < s2) red[t] += red[t + s2];
        __syncthreads();
    }
    float lse = m + logf(red[0]);
    __syncthreads();
    for (int i = t; i < O_DIM; i += 256) xr[i] = xr[i] - lse;
}

// ---------------------------------------------------------------------------
extern "C" void kernel_launch(void* const* d_in, const int* in_sizes, int n_in,
                              void* d_out, int out_size, void* d_ws, size_t ws_size,
                              hipStream_t stream)
{
    const float* input   = (const float*)d_in[0];   // [S,B,IN]
    const float* target  = (const float*)d_in[1];   // [T,B,H]
    const float* enc_Wih = (const float*)d_in[2];
    const float* enc_Whh = (const float*)d_in[3];
    const float* enc_bih = (const float*)d_in[4];
    const float* enc_bhh = (const float*)d_in[5];
    const float* attn_W  = (const float*)d_in[6];   // [S,2H]
    const float* attn_b  = (const float*)d_in[7];
    const float* comb_W  = (const float*)d_in[8];   // [H,2H]
    const float* comb_b  = (const float*)d_in[9];
    const float* dec_Wih = (const float*)d_in[10];
    const float* dec_Whh = (const float*)d_in[11];
    const float* dec_bih = (const float*)d_in[12];
    const float* dec_bhh = (const float*)d_in[13];
    const float* out_W   = (const float*)d_in[14];
    const float* out_b   = (const float*)d_in[15];
    float* out = (float*)d_out;                     // [B,O] fp32

    // ---- workspace layout ----
    char* p = (char*)d_ws;
    auto alloc = [&](size_t bytes) {
        char* r = p; p += (bytes + 255) & ~(size_t)255; return r;
    };
    unsigned short* wWhh  = (unsigned short*)alloc((size_t)H3 * H_DIM * 2);
    unsigned short* wDih  = (unsigned short*)alloc((size_t)H3 * H_DIM * 2);
    unsigned short* wDhh  = (unsigned short*)alloc((size_t)H3 * H_DIM * 2);
    unsigned short* wCc   = (unsigned short*)alloc((size_t)H_DIM * H_DIM * 2);
    unsigned short* wCx   = (unsigned short*)alloc((size_t)H_DIM * H_DIM * 2);
    unsigned short* wO    = (unsigned short*)alloc((size_t)O_DIM * H_DIM * 2);
    unsigned short* wAhT  = (unsigned short*)alloc((size_t)H_DIM * S_LEN * 2);
    unsigned short* wAx   = (unsigned short*)alloc((size_t)S_LEN * H_DIM * 2);
    unsigned short* wIhp  = (unsigned short*)alloc((size_t)H3 * INP * 2);
    unsigned short* xbp   = (unsigned short*)alloc((size_t)S_LEN * BATCH * INP * 2);
    unsigned short* encb  = (unsigned short*)alloc((size_t)S_LEN * BATCH * H_DIM * 2);
    unsigned short* combx = (unsigned short*)alloc((size_t)(T_LEN - 1) * BATCH * H_DIM * 2);
    unsigned short* attnx = (unsigned short*)alloc((size_t)(T_LEN - 1) * BATCH * S_LEN * 2);
    float*          h     = (float*)alloc((size_t)BATCH * H_DIM * 4);
    unsigned short* hbA   = (unsigned short*)alloc((size_t)BATCH * H_DIM * 2);
    unsigned short* hbB   = (unsigned short*)alloc((size_t)BATCH * H_DIM * 2);
    unsigned short* ctx   = (unsigned short*)alloc((size_t)BATCH * H_DIM * 2);
    unsigned short* comb  = (unsigned short*)alloc((size_t)BATCH * H_DIM * 2);
    unsigned short* encWc = (unsigned short*)alloc((size_t)S_LEN * BATCH * H_DIM * 2);
    const bool fuse = ((size_t)(p - (char*)d_ws) <= ws_size);
    // targetb overlays encb: consumed (attnx/combx gemms) before encoder
    // writes encb.
    unsigned short* targetb = encb;

    const dim3 blk(256);

    hipMemsetAsync(h,   0, (size_t)BATCH * H_DIM * 4, stream);
    hipMemsetAsync(hbA, 0, (size_t)BATCH * H_DIM * 2, stream);

    // ---- one fused convert launch ----
    cvt_all<<<2048, blk, 0, stream>>>(
        enc_Whh, dec_Wih, dec_Whh, comb_W, out_W, attn_W, enc_Wih, input, target,
        wWhh, wDih, wDhh, wCc, wCx, wO, wAx, wAhT, wIhp, xbp, targetb);

    const int MT = (T_LEN - 1) * BATCH;  // 15872
    // attnx = target @ attn_W[:, :H]^T + attn_b
    gemm_k<64, 64><<<dim3(1, MT / 64), blk, 0, stream>>>(
        targetb, H_DIM, wAx, H_DIM, attn_b,
        nullptr, nullptr, 0, nullptr, attnx, S_LEN, H_DIM, 1 | 32);
    // combx = target @ comb_W[:, :H]^T + comb_b
    gemm_k<128, 128><<<dim3(H_DIM / 128, MT / 128), blk, 0, stream>>>(
        targetb, H_DIM, wCx, H_DIM, comb_b,
        nullptr, nullptr, 0, nullptr, combx, H_DIM, H_DIM, 1 | 32);

    const dim3 grid_gru(H_DIM / 16, BATCH / 32);   // 64 x 16 = 1024 blocks
    unsigned short* hcur = hbA;
    unsigned short* hnxt = hbB;

    // ---------------- encoder: one kernel per step ----------------
    for (int s = 0; s < S_LEN; s++) {
        gru_gemm<<<grid_gru, blk, 0, stream>>>(
            xbp + (size_t)s * BATCH * INP, INP, wIhp, INP, INP,
            hcur, wWhh, enc_bih, enc_bhh, h, h, hnxt,
            encb + (size_t)s * BATCH * H_DIM);
        unsigned short* tmp = hcur; hcur = hnxt; hnxt = tmp;
    }

    if (fuse) {
        // encWc[l] = encb[l] @ wCc^T  (one parallel GEMM, M = 64*512)
        gemm_k<128, 128><<<dim3(H_DIM / 128, S_LEN * BATCH / 128), blk, 0, stream>>>(
            encb, H_DIM, wCc, H_DIM, nullptr,
            nullptr, nullptr, 0, nullptr, encWc, H_DIM, H_DIM, 32);
        // ---------------- decoder: TWO kernels per step ----------------
        for (int t = 0; t < T_LEN - 1; t++) {
            attn_comb<<<BATCH, blk, 0, stream>>>(
                hcur, wAhT, attnx + (size_t)t * BATCH * S_LEN, encWc,
                combx + (size_t)t * BATCH * H_DIM, comb);
            gru_gemm<<<grid_gru, blk, 0, stream>>>(
                comb, H_DIM, wDih, H_DIM, H_DIM,
                hcur, wDhh, dec_bih, dec_bhh, h, h, hnxt, nullptr);
            unsigned short* tmp = hcur; hcur = hnxt; hnxt = tmp;
        }
    } else {
        // fallback: 3 kernels per step (no encWc buffer)
        for (int t = 0; t < T_LEN - 1; t++) {
            attn_ctx<<<BATCH, blk, 0, stream>>>(
                hcur, wAhT, attnx + (size_t)t * BATCH * S_LEN, encb, ctx);
            gemm_k<32, 64><<<dim3(H_DIM / 64, BATCH / 32), blk, 0, stream>>>(
                ctx, H_DIM, wCc, H_DIM, nullptr,
                nullptr, combx + (size_t)t * BATCH * H_DIM, H_DIM,
                nullptr, comb, H_DIM, H_DIM, 4 | 8 | 32);
            gru_gemm<<<grid_gru, blk, 0, stream>>>(
                comb, H_DIM, wDih, H_DIM, H_DIM,
                hcur, wDhh, dec_bih, dec_bhh, h, h, hnxt, nullptr);
            unsigned short* tmp = hcur; hcur = hnxt; hnxt = tmp;
        }
    }

    // ---------------- output ----------------
    gemm_k<32, 64><<<dim3(O_DIM / 64, BATCH / 32), blk, 0, stream>>>(
        hcur, H_DIM, wO, H_DIM, out_b,
        nullptr, nullptr, 0, out, nullptr, O_DIM, H_DIM, 1 | 16);
    log_softmax1024<<<BATCH, blk, 0, stream>>>(out);
}